// Round 11
// baseline (187.154 us; speedup 1.0000x reference)
//
#include <hip/hip_runtime.h>
#include <math.h>

#define TOK 8192
#define DM 1024
#define EPSF 1e-5f

typedef __attribute__((ext_vector_type(8))) short short8;
typedef __attribute__((ext_vector_type(4))) float f32x4;

static __device__ __forceinline__ ushort f2bf(float f) {
  unsigned u = __float_as_uint(f);
  unsigned r = (u + 0x7fffu + ((u >> 16) & 1u)) >> 16;
  return (ushort)r;
}
static __device__ __forceinline__ float bf2f(ushort u) {
  return __uint_as_float((unsigned)u << 16);
}

static __device__ __forceinline__ void gload_lds16(const ushort* g, ushort* l) {
  __builtin_amdgcn_global_load_lds((const __attribute__((address_space(1))) void*)g,
                                   (__attribute__((address_space(3))) void*)l, 16, 0, 0);
}

// bank-aware swizzle for the C-staging tile (stride 128 ushorts = 256B)
static __device__ __forceinline__ int cswz(int row) {
  return (((row & 7) ^ ((row >> 3) & 7)) << 3);
}

// ---- merged prep: LayerNorm+cvt (blocks 0..8191) | weight transpose (rest)
__global__ __launch_bounds__(256) void prep_k(
    const float* __restrict__ x, const float* __restrict__ g,
    const float* __restrict__ b, ushort* __restrict__ x_b,
    ushort* __restrict__ xn_b,
    const float* __restrict__ Wg, const float* __restrict__ Wq,
    const float* __restrict__ Wp, ushort* __restrict__ Wtg,
    ushort* __restrict__ Wtq, ushort* __restrict__ Wtp) {
  __shared__ ushort tile[32][33];
  __shared__ float red[8];
  if (blockIdx.x < 8192) {
    int row = blockIdx.x;
    const float4* xr = (const float4*)(x + (size_t)row * DM);
    float4 v = xr[threadIdx.x];
    ushort4 xb4;
    xb4.x = f2bf(v.x); xb4.y = f2bf(v.y); xb4.z = f2bf(v.z); xb4.w = f2bf(v.w);
    ((ushort4*)(x_b + (size_t)row * DM))[threadIdx.x] = xb4;
    float s = v.x + v.y + v.z + v.w;
#pragma unroll
    for (int o = 32; o > 0; o >>= 1) s += __shfl_down(s, o, 64);
    int lane = threadIdx.x & 63, w = threadIdx.x >> 6;
    if (lane == 0) red[w] = s;
    __syncthreads();
    float mu = (red[0] + red[1] + red[2] + red[3]) * (1.0f / DM);
    float dx = v.x - mu, dy = v.y - mu, dz = v.z - mu, dw = v.w - mu;
    float ss = dx * dx + dy * dy + dz * dz + dw * dw;
#pragma unroll
    for (int o = 32; o > 0; o >>= 1) ss += __shfl_down(ss, o, 64);
    if (lane == 0) red[4 + w] = ss;
    __syncthreads();
    float var = (red[4] + red[5] + red[6] + red[7]) * (1.0f / DM);
    float rstd = rsqrtf(var + EPSF);
    float4 gg = ((const float4*)g)[threadIdx.x];
    float4 bb = ((const float4*)b)[threadIdx.x];
    ushort4 o4;
    o4.x = f2bf(dx * rstd * gg.x + bb.x);
    o4.y = f2bf(dy * rstd * gg.y + bb.y);
    o4.z = f2bf(dz * rstd * gg.z + bb.z);
    o4.w = f2bf(dw * rstd * gg.w + bb.w);
    ((ushort4*)(xn_b + (size_t)row * DM))[threadIdx.x] = o4;
  } else {
    int bid = blockIdx.x - 8192;
    const float* W; ushort* Wt; int N; int local;
    if (bid < 1024)      { W = Wg; Wt = Wtg; N = 1024; local = bid; }
    else if (bid < 4096) { W = Wq; Wt = Wtq; N = 3072; local = bid - 1024; }
    else                 { W = Wp; Wt = Wtp; N = 1024; local = bid - 4096; }
    int ntiles = N >> 5;
    int n0 = (local % ntiles) * 32, k0 = (local / ntiles) * 32;
    int tx = threadIdx.x & 31, ty = threadIdx.x >> 5;
#pragma unroll
    for (int i = 0; i < 4; i++) {
      int k = ty + i * 8;
      tile[k][tx] = f2bf(W[(size_t)(k0 + k) * N + n0 + tx]);
    }
    __syncthreads();
#pragma unroll
    for (int i = 0; i < 4; i++) {
      int n = ty + i * 8;
      Wt[(size_t)(n0 + n) * 1024 + k0 + tx] = tile[tx][n];
    }
  }
}

// ======== 128x128 MFMA GEMM, 2-phase stage-ahead double-buffered =========
#define BM 128
#define BN 128
#define BK 64

static __device__ __forceinline__ void stage_tile128(
    const ushort* __restrict__ A, const ushort* __restrict__ Bt,
    int m0, int n0, int k0, int K, ushort* As, ushort* Bs, int w, int lane) {
#pragma unroll
  for (int j = 0; j < 4; j++) {
    int lu = (w * 4 + j) * 64 + lane;
    int r = lu >> 3;
    int kb = (lu & 7) ^ (r & 7);
    gload_lds16(A + (size_t)(m0 + r) * K + k0 + kb * 8, As + (w * 4 + j) * 512);
    gload_lds16(Bt + (size_t)(n0 + r) * K + k0 + kb * 8, Bs + (w * 4 + j) * 512);
  }
}

static __device__ __forceinline__ void compute_tile128(
    const ushort* as, const ushort* bs, int wr, int wc, int lane, f32x4 acc[4][4]) {
#pragma unroll
  for (int ks = 0; ks < 2; ks++) {
    short8 af[4], bfr[4];
    int kq = ks * 4 + (lane >> 4);
#pragma unroll
    for (int f = 0; f < 4; f++) {
      int ra = wr * 64 + f * 16 + (lane & 15);
      af[f] = *(const short8*)&as[(ra * 8 + (kq ^ (ra & 7))) * 8];
      int rb = wc * 64 + f * 16 + (lane & 15);
      bfr[f] = *(const short8*)&bs[(rb * 8 + (kq ^ (rb & 7))) * 8];
    }
#pragma unroll
    for (int i = 0; i < 4; i++)
#pragma unroll
      for (int j2 = 0; j2 < 4; j2++)
        acc[i][j2] = __builtin_amdgcn_mfma_f32_16x16x32_bf16(af[i], bfr[j2], acc[i][j2], 0, 0, 0);
  }
}

// 2-phase loop: sync (drains tile t) -> stage(t+1) -> compute(t).
#define GEMM_LOOP128(A_, B_, m0_, n0_, K_)                                       \
  f32x4 acc[4][4] = {};                                                          \
  stage_tile128(A_, B_, m0_, n0_, 0, K_, sh, sh + 16384, w, lane);               \
  int nt = (K_) / BK;                                                            \
  for (int t = 0; t < nt; t++) {                                                 \
    __syncthreads();                                                             \
    if (t + 1 < nt)                                                              \
      stage_tile128(A_, B_, m0_, n0_, (t + 1) * BK, K_,                          \
                    sh + ((t + 1) & 1) * 8192, sh + 16384 + ((t + 1) & 1) * 8192,\
                    w, lane);                                                    \
    compute_tile128(sh + (t & 1) * 8192, sh + 16384 + (t & 1) * 8192,            \
                    wr, wc, lane, acc);                                          \
  }                                                                              \
  __syncthreads();

// ---------------- proj GEMM: fp32 out ----------------
__global__ __launch_bounds__(256) void gemm_bf16_k(
    const ushort* __restrict__ A, const ushort* __restrict__ Bt,
    const float* __restrict__ bias, float* __restrict__ Cf, int ldc, int K) {
  __shared__ __align__(16) ushort sh[32768];
  int tid = threadIdx.x, lane = tid & 63, w = tid >> 6;
  int m0 = blockIdx.y * BM, n0 = blockIdx.x * BN;
  int wr = w >> 1, wc = w & 1;
  GEMM_LOOP128(A, Bt, m0, n0, K)
#pragma unroll
  for (int i = 0; i < 4; i++) {
#pragma unroll
    for (int j2 = 0; j2 < 4; j2++) {
      int col = n0 + wc * 64 + j2 * 16 + (lane & 15);
      float bv = bias[col];
#pragma unroll
      for (int r = 0; r < 4; r++) {
        int row = m0 + wr * 64 + i * 16 + (lane >> 4) * 4 + r;
        Cf[(size_t)row * ldc + col] = acc[i][j2][r] + bv;
      }
    }
  }
}

// ------- gate GEMM: sigmoid -> bf16 out + per-row partial sums -----------
__global__ __launch_bounds__(256) void gemm_gate_k(
    const ushort* __restrict__ A, const ushort* __restrict__ Bt,
    const float* __restrict__ bias, ushort* __restrict__ Cb, int ldc, int K,
    float* __restrict__ gpart) {
  __shared__ __align__(16) ushort sh[32768];
  int tid = threadIdx.x, lane = tid & 63, w = tid >> 6;
  int m0 = blockIdx.y * BM, n0 = blockIdx.x * BN;
  int wr = w >> 1, wc = w & 1;
  GEMM_LOOP128(A, Bt, m0, n0, K)
  int lr = lane & 15, lg = lane >> 4;
  float* rs2 = (float*)sh;  // [2][128]
#pragma unroll
  for (int i = 0; i < 4; i++) {
#pragma unroll
    for (int r = 0; r < 4; r++) {
      float rsum = 0.0f;
      int row = m0 + wr * 64 + i * 16 + lg * 4 + r;
#pragma unroll
      for (int j2 = 0; j2 < 4; j2++) {
        int col = n0 + wc * 64 + j2 * 16 + lr;
        float v = 1.0f / (1.0f + __expf(-(acc[i][j2][r] + bias[col])));
        rsum += v;
        Cb[(size_t)row * ldc + col] = f2bf(v);
      }
#pragma unroll
      for (int o = 1; o < 16; o <<= 1) rsum += __shfl_xor(rsum, o, 64);
      if (lr == 0) rs2[wc * 128 + wr * 64 + i * 16 + lg * 4 + r] = rsum;
    }
  }
  __syncthreads();
  if (tid < 128)
    gpart[(size_t)(m0 + tid) * 8 + blockIdx.x] = rs2[tid] + rs2[128 + tid];
}

// ---------------- qkv GEMM with LDS-staged coalesced epilogue ------------
__global__ __launch_bounds__(256) void gemm_qkv_k(
    const ushort* __restrict__ A, const ushort* __restrict__ Bt,
    const float* __restrict__ bias, const ushort* __restrict__ gate_b,
    const float* __restrict__ gpart,
    ushort* __restrict__ qb, ushort* __restrict__ kb,
    ushort* __restrict__ kt, ushort* __restrict__ vt, int K) {
  __shared__ __align__(16) ushort sh[32768];
  __shared__ float ginvs[128];
  int tid = threadIdx.x, lane = tid & 63, w = tid >> 6;
  int m0 = blockIdx.y * BM, n0 = blockIdx.x * BN;
  int wr = w >> 1, wc = w & 1;
  GEMM_LOOP128(A, Bt, m0, n0, K)
  // ---- epilogue ----
  int region = n0 >> 10;  // 0=q, 1=k, 2=v
  int n0b = n0 & 1023;
  int h0 = n0b >> 6;
  if (region < 2) {
    if (tid < 128) {
      const float4* gp = (const float4*)&gpart[(size_t)(m0 + tid) * 8];
      float4 s0 = gp[0], s1 = gp[1];
      float s = s0.x + s0.y + s0.z + s0.w + s1.x + s1.y + s1.z + s1.w;
      ginvs[tid] = 1.0f / (s * (1.0f / DM) + EPSF);
    }
#pragma unroll
    for (int it = 0; it < 8; it++) {
      int e = it * 256 + tid;
      int row = e >> 4, ch = e & 15;
      *(short8*)&sh[row * 132 + ch * 8] =
          *(const short8*)&gate_b[(size_t)(m0 + row) * DM + n0b + ch * 8];
    }
    __syncthreads();
#pragma unroll
    for (int i = 0; i < 4; i++) {
#pragma unroll
      for (int j2 = 0; j2 < 4; j2++) {
        int cl = wc * 64 + j2 * 16 + (lane & 15);
        float bv = bias[n0 + cl];
        int rl0 = wr * 64 + i * 16 + (lane >> 4) * 4;
#pragma unroll
        for (int r = 0; r < 4; r++) {
          float gv = bf2f(sh[(rl0 + r) * 132 + cl]) * ginvs[rl0 + r];
          float v = (acc[i][j2][r] + bv) * gv;
          v = fmaxf(v, 0.0f);
          acc[i][j2][r] = v * v + EPSF;
        }
      }
    }
    __syncthreads();
  } else {
#pragma unroll
    for (int i = 0; i < 4; i++)
#pragma unroll
      for (int j2 = 0; j2 < 4; j2++) {
        int cl = wc * 64 + j2 * 16 + (lane & 15);
        float bv = bias[n0 + cl];
#pragma unroll
        for (int r = 0; r < 4; r++) acc[i][j2][r] += bv;
      }
  }
  // pack C tile into LDS, swizzled
#pragma unroll
  for (int i = 0; i < 4; i++) {
#pragma unroll
    for (int j2 = 0; j2 < 4; j2++) {
      int cl = wc * 64 + j2 * 16 + (lane & 15);
      int rl0 = wr * 64 + i * 16 + (lane >> 4) * 4;
#pragma unroll
      for (int r = 0; r < 4; r++) {
        int row = rl0 + r;
        sh[row * 128 + (cl ^ cswz(row))] = f2bf(acc[i][j2][r]);
      }
    }
  }
  __syncthreads();
  // coalesced stores
  if (region < 2) {
    ushort* dstRM = (region == 0) ? qb : kb;
#pragma unroll
    for (int it = 0; it < 8; it++) {
      int e = it * 256 + tid;
      int row = e >> 4, ch = e & 15;
      short8 val = *(const short8*)&sh[row * 128 + ((ch * 8) ^ cswz(row))];
      int tglob = m0 + row;
      size_t bh2 = (size_t)(tglob >> 11) * 16 + h0 + (ch >> 3);
      *(short8*)&dstRM[(bh2 * 2048 + (tglob & 2047)) * 64 + (ch & 7) * 8] = val;
    }
  }
  if (region >= 1) {
    ushort* dstT = (region == 1) ? kt : vt;
#pragma unroll
    for (int it = 0; it < 8; it++) {
      int e = it * 256 + tid;
      int tch = e & 15, dkrow = e >> 4;
      short8 val;
#pragma unroll
      for (int j = 0; j < 8; j++) {
        int row = tch * 8 + j;
        val[j] = (short)sh[row * 128 + (dkrow ^ cswz(row))];
      }
      int tglob0 = m0 + tch * 8;
      size_t bh2 = (size_t)(tglob0 >> 11) * 16 + h0 + (dkrow >> 6);
      *(short8*)&dstT[(bh2 * 64 + (dkrow & 63)) * 2048 + (tglob0 & 2047)] = val;
    }
  }
}

// ---- fused chunk-KV + exclusive prefix (running prefix = MFMA C-operand) --
// 2-deep chunk prefetch.
__global__ __launch_bounds__(256) void chunkpfx_k(const ushort* __restrict__ kt,
                                                  const ushort* __restrict__ vt,
                                                  ushort* __restrict__ KVb,
                                                  float* __restrict__ ksum) {
  int bid = blockIdx.x;
  int bh = (bid & 7) | ((bid >> 5) << 3);
  int dvs = (bid >> 3) & 3;
  int tid = threadIdx.x, l = tid & 63, w = tid >> 6;
  int lg = l >> 4;
  const ushort* vT = vt + ((size_t)bh * 64 + dvs * 16 + (l & 15)) * 2048;
  const ushort* kT = kt + ((size_t)bh * 64 + w * 16 + (l & 15)) * 2048;
  f32x4 run = {0.f, 0.f, 0.f, 0.f};
  float runks = 0.0f;
  short8 a0 = *(const short8*)&vT[lg * 8];
  short8 a1 = *(const short8*)&vT[32 + lg * 8];
  short8 b0 = *(const short8*)&kT[lg * 8];
  short8 b1 = *(const short8*)&kT[32 + lg * 8];
  short8 na0 = *(const short8*)&vT[64 + lg * 8];
  short8 na1 = *(const short8*)&vT[96 + lg * 8];
  short8 nb0 = *(const short8*)&kT[64 + lg * 8];
  short8 nb1 = *(const short8*)&kT[96 + lg * 8];
  for (int c = 0; c < 32; c++) {
    ushort* dst = KVb + ((size_t)bh * 32 + c) * 4096 +
                  (size_t)(dvs * 16 + lg * 4) * 64 + w * 16 + (l & 15);
    dst[0] = f2bf(run[0]); dst[64] = f2bf(run[1]);
    dst[128] = f2bf(run[2]); dst[192] = f2bf(run[3]);
    if (dvs == 0) {
      float s = 0.f;
#pragma unroll
      for (int j = 0; j < 8; j++) s += bf2f((ushort)b0[j]) + bf2f((ushort)b1[j]);
      s += __shfl_xor(s, 16, 64);
      s += __shfl_xor(s, 32, 64);
      if (l < 16) ksum[((size_t)bh * 32 + c) * 64 + w * 16 + l] = runks;
      runks += s;
    }
    int cn = (c + 2) & 31;  // clamped prefetch (wraps on last 2 iters, unused)
    short8 ta0 = *(const short8*)&vT[cn * 64 + lg * 8];
    short8 ta1 = *(const short8*)&vT[cn * 64 + 32 + lg * 8];
    short8 tb0 = *(const short8*)&kT[cn * 64 + lg * 8];
    short8 tb1 = *(const short8*)&kT[cn * 64 + 32 + lg * 8];
    run = __builtin_amdgcn_mfma_f32_16x16x32_bf16(a0, b0, run, 0, 0, 0);
    run = __builtin_amdgcn_mfma_f32_16x16x32_bf16(a1, b1, run, 0, 0, 0);
    a0 = na0; a1 = na1; b0 = nb0; b1 = nb1;
    na0 = ta0; na1 = ta1; nb0 = tb0; nb1 = tb1;
  }
}

// ---------------- pass 3: O^T[dv][t] = KVb·Q + vt·S, S^T = mfma(K,Q) ------
// Output staged in swizzled LDS -> fully coalesced 128B row-segment stores.
__global__ __launch_bounds__(256) void attn_k(
    const ushort* __restrict__ qb, const ushort* __restrict__ kb,
    const ushort* __restrict__ vt, const ushort* __restrict__ KVb,
    const float* __restrict__ ks, ushort* __restrict__ attnout) {
  int c = blockIdx.x, bh = blockIdx.y;
  int b = bh >> 4, h = bh & 15;
  const ushort* qB = qb + ((size_t)bh * 2048 + (size_t)c * 64) * 64;
  const ushort* kB = kb + ((size_t)bh * 2048 + (size_t)c * 64) * 64;
  const ushort* vT = vt + (size_t)bh * 64 * 2048 + (size_t)c * 64;
  const ushort* kvB = KVb + ((size_t)bh * 32 + c) * 4096;
  const float* ksP = ks + ((size_t)bh * 32 + c) * 64;
  __shared__ __align__(16) char SL[64 * 128];
  __shared__ __align__(16) ushort OL[64 * 64];  // [t][dv], 8B units XOR-swizzled
  __shared__ float denp[4][64];
  __shared__ float den2p[4][64];
  __shared__ float invden[64];
  int tid = threadIdx.x, l = tid & 63, w = tid >> 6;
  int lr = l & 15, lg = l >> 4;
  {
    short8 q0 = *(const short8*)&qB[(size_t)l * 64 + w * 16];
    short8 q1 = *(const short8*)&qB[(size_t)l * 64 + w * 16 + 8];
    const float4* k4 = (const float4*)(ksP + w * 16);
    float4 ka0 = k4[0], ka1 = k4[1], ka2 = k4[2], ka3 = k4[3];
    float d2 = bf2f((ushort)q0[0]) * ka0.x + bf2f((ushort)q0[1]) * ka0.y +
               bf2f((ushort)q0[2]) * ka0.z + bf2f((ushort)q0[3]) * ka0.w +
               bf2f((ushort)q0[4]) * ka1.x + bf2f((ushort)q0[5]) * ka1.y +
               bf2f((ushort)q0[6]) * ka1.z + bf2f((ushort)q0[7]) * ka1.w +
               bf2f((ushort)q1[0]) * ka2.x + bf2f((ushort)q1[1]) * ka2.y +
               bf2f((ushort)q1[2]) * ka2.z + bf2f((ushort)q1[3]) * ka2.w +
               bf2f((ushort)q1[4]) * ka3.x + bf2f((ushort)q1[5]) * ka3.y +
               bf2f((ushort)q1[6]) * ka3.z + bf2f((ushort)q1[7]) * ka3.w;
    den2p[w][l] = d2;
  }
#pragma unroll
  for (int n = 0; n < 4; n++) {
    f32x4 sa = {0.f, 0.f, 0.f, 0.f};
    {
      short8 a0 = *(const short8*)&kB[(size_t)(w * 16 + lr) * 64 + lg * 8];
      short8 bq0 = *(const short8*)&qB[(size_t)(n * 16 + lr) * 64 + lg * 8];
      short8 a1 = *(const short8*)&kB[(size_t)(w * 16 + lr) * 64 + 32 + lg * 8];
      short8 bq1 = *(const short8*)&qB[(size_t)(n * 16 + lr) * 64 + 32 + lg * 8];
      __builtin_amdgcn_s_setprio(1);
      sa = __builtin_amdgcn_mfma_f32_16x16x32_bf16(a0, bq0, sa, 0, 0, 0);
      sa = __builtin_amdgcn_mfma_f32_16x16x32_bf16(a1, bq1, sa, 0, 0, 0);
      __builtin_amdgcn_s_setprio(0);
    }
    int t = n * 16 + lr;
    int s0 = w * 16 + lg * 4;
    float dsum = 0.0f;
    ushort sb[4];
#pragma unroll
    for (int r = 0; r < 4; r++) {
      float v = (s0 + r <= t) ? sa[r] : 0.0f;
      dsum += v;
      sb[r] = f2bf(v);
    }
    dsum += __shfl_xor(dsum, 16, 64);
    dsum += __shfl_xor(dsum, 32, 64);
    if (l < 16) denp[w][n * 16 + l] = dsum;
    int u = (s0 >> 3) ^ (t & 7);
    uint2 p;
    p.x = sb[0] | ((unsigned)sb[1] << 16);
    p.y = sb[2] | ((unsigned)sb[3] << 16);
    *(uint2*)&SL[t * 128 + u * 16 + (s0 & 7) * 2] = p;
  }
  __syncthreads();
  if (tid < 64) {
    float den = denp[0][tid] + denp[1][tid] + denp[2][tid] + denp[3][tid] +
                den2p[0][tid] + den2p[1][tid] + den2p[2][tid] + den2p[3][tid] + EPSF;
    invden[tid] = 1.0f / den;
  }
  __syncthreads();
#pragma unroll
  for (int n = 0; n < 4; n++) {
    f32x4 oa = {0.f, 0.f, 0.f, 0.f};
    int t = n * 16 + lr;
    {
      short8 a0 = *(const short8*)&kvB[(size_t)(w * 16 + lr) * 64 + lg * 8];
      short8 bq0 = *(const short8*)&qB[(size_t)(n * 16 + lr) * 64 + lg * 8];
      short8 a1 = *(const short8*)&kvB[(size_t)(w * 16 + lr) * 64 + 32 + lg * 8];
      short8 bq1 = *(const short8*)&qB[(size_t)(n * 16 + lr) * 64 + 32 + lg * 8];
      short8 v0 = *(const short8*)&vT[(size_t)(w * 16 + lr) * 2048 + lg * 8];
      int u0 = lg ^ (t & 7);
      short8 s0v = *(const short8*)&SL[t * 128 + u0 * 16];
      short8 v1 = *(const short8*)&vT[(size_t)(w * 16 + lr) * 2048 + 32 + lg * 8];
      int u1 = (4 + lg) ^ (t & 7);
      short8 s1v = *(const short8*)&SL[t * 128 + u1 * 16];
      __builtin_amdgcn_s_setprio(1);
      oa = __builtin_amdgcn_mfma_f32_16x16x32_bf16(a0, bq0, oa, 0, 0, 0);
      oa = __builtin_amdgcn_mfma_f32_16x16x32_bf16(v0, s0v, oa, 0, 0, 0);
      oa = __builtin_amdgcn_mfma_f32_16x16x32_bf16(a1, bq1, oa, 0, 0, 0);
      oa = __builtin_amdgcn_mfma_f32_16x16x32_bf16(v1, s1v, oa, 0, 0, 0);
      __builtin_amdgcn_s_setprio(0);
    }
    float iv = invden[t];
    ushort ob[4];
#pragma unroll
    for (int r = 0; r < 4; r++) ob[r] = f2bf(oa[r] * iv);
    // stage into OL: row t, 8B unit j = w*4+lg, swizzled j' = j ^ (t&14)
    int jp = (w * 4 + lg) ^ (lr & 14);  // t&14 == lr&14 since t = n*16+lr
    uint2 p;
    p.x = ob[0] | ((unsigned)ob[1] << 16);
    p.y = ob[2] | ((unsigned)ob[3] << 16);
    *(uint2*)&OL[t * 64 + jp * 4] = p;
  }
  __syncthreads();
  // coalesced output: 128B contiguous per token row
  size_t tok0 = (size_t)b * 2048 + (size_t)c * 64;
#pragma unroll
  for (int it = 0; it < 2; it++) {
    int e = it * 256 + tid;
    int row = e >> 3, ch = e & 7;           // 16B chunk ch of row
    int cs = ch ^ ((row >> 1) & 7);         // inverse swizzle (16B units)
    short8 val = *(const short8*)&OL[row * 64 + cs * 8];
    *(short8*)&attnout[(tok0 + row) * 1024 + h * 64 + ch * 8] = val;
  }
}

extern "C" void kernel_launch(void* const* d_in, const int* in_sizes, int n_in,
                              void* d_out, int out_size, void* d_ws, size_t ws_size,
                              hipStream_t stream) {
  const float* x      = (const float*)d_in[0];
  const float* ln_g   = (const float*)d_in[1];
  const float* ln_b   = (const float*)d_in[2];
  const float* W_qkv  = (const float*)d_in[3];
  const float* b_qkv  = (const float*)d_in[4];
  const float* W_gate = (const float*)d_in[5];
  const float* b_gate = (const float*)d_in[6];
  const float* W_proj = (const float*)d_in[7];
  const float* b_proj = (const float*)d_in[8];
  float* out = (float*)d_out;

  char* wsb = (char*)d_ws;
  const size_t TD = (size_t)TOK * DM;
  const size_t SLOT = TD * 2;
  ushort* x_b     = (ushort*)(wsb + 0 * SLOT);  // dead after gate GEMM
  ushort* attnout = (ushort*)(wsb + 0 * SLOT);
  ushort* xn_b    = (ushort*)(wsb + 1 * SLOT);
  ushort* qb      = (ushort*)(wsb + 2 * SLOT);
  ushort* kb      = (ushort*)(wsb + 3 * SLOT);
  ushort* kt      = (ushort*)(wsb + 4 * SLOT);
  ushort* vt      = (ushort*)(wsb + 5 * SLOT);
  ushort* gate_b  = (ushort*)(wsb + 6 * SLOT);  // slots 6-7
  // slot 8: Wt_qkv @0 (6.3MB) + Wt_gate @8MB (2.1MB); both dead -> KVb
  ushort* Wt_qkv  = (ushort*)(wsb + 8 * SLOT);
  ushort* Wt_gate = (ushort*)(wsb + 8 * SLOT + (size_t)8 * 1024 * 1024);
  ushort* KVb     = (ushort*)(wsb + 8 * SLOT);
  ushort* Wt_proj = (ushort*)(wsb + 9 * SLOT);
  float*  ksum    = (float*)(wsb + 9 * SLOT + (size_t)8 * 1024 * 1024);   // 512 KB
  float*  gpart   = (float*)(wsb + 9 * SLOT + (size_t)12 * 1024 * 1024);  // 256 KB

  // 1) LayerNorm + x->bf16 + all weight transposes, one launch
  prep_k<<<8192 + 5120, 256, 0, stream>>>(x, ln_g, ln_b, x_b, xn_b,
                                          W_gate, W_qkv, W_proj,
                                          Wt_gate, Wt_qkv, Wt_proj);
  // 2) gate = sigmoid(x @ W_gate + b_gate) -> bf16, + per-row partial sums
  gemm_gate_k<<<dim3(DM / BN, TOK / BM), 256, 0, stream>>>(x_b, Wt_gate, b_gate,
                                                           gate_b, DM, DM, gpart);
  // 3) qkv GEMM -> qb/kb + kt/vt (bf16), fused gate*ginv+relu^2
  gemm_qkv_k<<<dim3(3 * DM / BN, TOK / BM), 256, 0, stream>>>(xn_b, Wt_qkv, b_qkv, gate_b,
                                                              gpart, qb, kb, kt, vt, DM);
  // 4) fused chunk-KV + exclusive prefix -> KVb (bf16) + ksum (fp32)
  chunkpfx_k<<<256, 256, 0, stream>>>(kt, vt, KVb, ksum);
  // 5) chunk outputs -> attnout bf16 row-major
  attn_k<<<dim3(32, 64), 256, 0, stream>>>(qb, kb, vt, KVb, ksum, attnout);
  // 6) out = attn @ W_proj + b_proj (fp32 out)
  gemm_bf16_k<<<dim3(DM / BN, TOK / BM), 256, 0, stream>>>(attnout, Wt_proj, b_proj, out,
                                                           DM, DM);
}

// Round 12
// 183.705 us; speedup vs baseline: 1.0188x; 1.0188x over previous
//
#include <hip/hip_runtime.h>
#include <math.h>

#define TOK 8192
#define DM 1024
#define EPSF 1e-5f

typedef __attribute__((ext_vector_type(8))) short short8;
typedef __attribute__((ext_vector_type(4))) float f32x4;

static __device__ __forceinline__ ushort f2bf(float f) {
  unsigned u = __float_as_uint(f);
  unsigned r = (u + 0x7fffu + ((u >> 16) & 1u)) >> 16;
  return (ushort)r;
}
static __device__ __forceinline__ float bf2f(ushort u) {
  return __uint_as_float((unsigned)u << 16);
}

static __device__ __forceinline__ void gload_lds16(const ushort* g, ushort* l) {
  __builtin_amdgcn_global_load_lds((const __attribute__((address_space(1))) void*)g,
                                   (__attribute__((address_space(3))) void*)l, 16, 0, 0);
}

// bank-aware swizzle for the C-staging tile (stride 128 ushorts = 256B)
static __device__ __forceinline__ int cswz(int row) {
  return (((row & 7) ^ ((row >> 3) & 7)) << 3);
}

// ---- merged prep: LayerNorm+cvt (blocks 0..8191) | weight transpose (rest)
__global__ __launch_bounds__(256) void prep_k(
    const float* __restrict__ x, const float* __restrict__ g,
    const float* __restrict__ b, ushort* __restrict__ x_b,
    ushort* __restrict__ xn_b,
    const float* __restrict__ Wg, const float* __restrict__ Wq,
    const float* __restrict__ Wp, ushort* __restrict__ Wtg,
    ushort* __restrict__ Wtq, ushort* __restrict__ Wtp) {
  __shared__ ushort tile[32][33];
  __shared__ float red[8];
  if (blockIdx.x < 8192) {
    int row = blockIdx.x;
    const float4* xr = (const float4*)(x + (size_t)row * DM);
    float4 v = xr[threadIdx.x];
    ushort4 xb4;
    xb4.x = f2bf(v.x); xb4.y = f2bf(v.y); xb4.z = f2bf(v.z); xb4.w = f2bf(v.w);
    ((ushort4*)(x_b + (size_t)row * DM))[threadIdx.x] = xb4;
    float s = v.x + v.y + v.z + v.w;
#pragma unroll
    for (int o = 32; o > 0; o >>= 1) s += __shfl_down(s, o, 64);
    int lane = threadIdx.x & 63, w = threadIdx.x >> 6;
    if (lane == 0) red[w] = s;
    __syncthreads();
    float mu = (red[0] + red[1] + red[2] + red[3]) * (1.0f / DM);
    float dx = v.x - mu, dy = v.y - mu, dz = v.z - mu, dw = v.w - mu;
    float ss = dx * dx + dy * dy + dz * dz + dw * dw;
#pragma unroll
    for (int o = 32; o > 0; o >>= 1) ss += __shfl_down(ss, o, 64);
    if (lane == 0) red[4 + w] = ss;
    __syncthreads();
    float var = (red[4] + red[5] + red[6] + red[7]) * (1.0f / DM);
    float rstd = rsqrtf(var + EPSF);
    float4 gg = ((const float4*)g)[threadIdx.x];
    float4 bb = ((const float4*)b)[threadIdx.x];
    ushort4 o4;
    o4.x = f2bf(dx * rstd * gg.x + bb.x);
    o4.y = f2bf(dy * rstd * gg.y + bb.y);
    o4.z = f2bf(dz * rstd * gg.z + bb.z);
    o4.w = f2bf(dw * rstd * gg.w + bb.w);
    ((ushort4*)(xn_b + (size_t)row * DM))[threadIdx.x] = o4;
  } else {
    int bid = blockIdx.x - 8192;
    const float* W; ushort* Wt; int N; int local;
    if (bid < 1024)      { W = Wg; Wt = Wtg; N = 1024; local = bid; }
    else if (bid < 4096) { W = Wq; Wt = Wtq; N = 3072; local = bid - 1024; }
    else                 { W = Wp; Wt = Wtp; N = 1024; local = bid - 4096; }
    int ntiles = N >> 5;
    int n0 = (local % ntiles) * 32, k0 = (local / ntiles) * 32;
    int tx = threadIdx.x & 31, ty = threadIdx.x >> 5;
#pragma unroll
    for (int i = 0; i < 4; i++) {
      int k = ty + i * 8;
      tile[k][tx] = f2bf(W[(size_t)(k0 + k) * N + n0 + tx]);
    }
    __syncthreads();
#pragma unroll
    for (int i = 0; i < 4; i++) {
      int n = ty + i * 8;
      Wt[(size_t)(n0 + n) * 1024 + k0 + tx] = tile[tx][n];
    }
  }
}

// ======== 128x128 MFMA GEMM, 2-phase stage-ahead double-buffered =========
#define BM 128
#define BN 128
#define BK 64

static __device__ __forceinline__ void stage_tile128(
    const ushort* __restrict__ A, const ushort* __restrict__ Bt,
    int m0, int n0, int k0, int K, ushort* As, ushort* Bs, int w, int lane) {
#pragma unroll
  for (int j = 0; j < 4; j++) {
    int lu = (w * 4 + j) * 64 + lane;
    int r = lu >> 3;
    int kb = (lu & 7) ^ (r & 7);
    gload_lds16(A + (size_t)(m0 + r) * K + k0 + kb * 8, As + (w * 4 + j) * 512);
    gload_lds16(Bt + (size_t)(n0 + r) * K + k0 + kb * 8, Bs + (w * 4 + j) * 512);
  }
}

static __device__ __forceinline__ void compute_tile128(
    const ushort* as, const ushort* bs, int wr, int wc, int lane, f32x4 acc[4][4]) {
#pragma unroll
  for (int ks = 0; ks < 2; ks++) {
    short8 af[4], bfr[4];
    int kq = ks * 4 + (lane >> 4);
#pragma unroll
    for (int f = 0; f < 4; f++) {
      int ra = wr * 64 + f * 16 + (lane & 15);
      af[f] = *(const short8*)&as[(ra * 8 + (kq ^ (ra & 7))) * 8];
      int rb = wc * 64 + f * 16 + (lane & 15);
      bfr[f] = *(const short8*)&bs[(rb * 8 + (kq ^ (rb & 7))) * 8];
    }
#pragma unroll
    for (int i = 0; i < 4; i++)
#pragma unroll
      for (int j2 = 0; j2 < 4; j2++)
        acc[i][j2] = __builtin_amdgcn_mfma_f32_16x16x32_bf16(af[i], bfr[j2], acc[i][j2], 0, 0, 0);
  }
}

// 2-phase loop: sync (drains tile t) -> stage(t+1) -> compute(t).
#define GEMM_LOOP128(A_, B_, m0_, n0_, K_)                                       \
  f32x4 acc[4][4] = {};                                                          \
  stage_tile128(A_, B_, m0_, n0_, 0, K_, sh, sh + 16384, w, lane);               \
  int nt = (K_) / BK;                                                            \
  for (int t = 0; t < nt; t++) {                                                 \
    __syncthreads();                                                             \
    if (t + 1 < nt)                                                              \
      stage_tile128(A_, B_, m0_, n0_, (t + 1) * BK, K_,                          \
                    sh + ((t + 1) & 1) * 8192, sh + 16384 + ((t + 1) & 1) * 8192,\
                    w, lane);                                                    \
    compute_tile128(sh + (t & 1) * 8192, sh + 16384 + (t & 1) * 8192,            \
                    wr, wc, lane, acc);                                          \
  }                                                                              \
  __syncthreads();

// ---------------- proj GEMM: fp32 out ----------------
__global__ __launch_bounds__(256) void gemm_bf16_k(
    const ushort* __restrict__ A, const ushort* __restrict__ Bt,
    const float* __restrict__ bias, float* __restrict__ Cf, int ldc, int K) {
  __shared__ __align__(16) ushort sh[32768];
  int tid = threadIdx.x, lane = tid & 63, w = tid >> 6;
  int m0 = blockIdx.y * BM, n0 = blockIdx.x * BN;
  int wr = w >> 1, wc = w & 1;
  GEMM_LOOP128(A, Bt, m0, n0, K)
#pragma unroll
  for (int i = 0; i < 4; i++) {
#pragma unroll
    for (int j2 = 0; j2 < 4; j2++) {
      int col = n0 + wc * 64 + j2 * 16 + (lane & 15);
      float bv = bias[col];
#pragma unroll
      for (int r = 0; r < 4; r++) {
        int row = m0 + wr * 64 + i * 16 + (lane >> 4) * 4 + r;
        Cf[(size_t)row * ldc + col] = acc[i][j2][r] + bv;
      }
    }
  }
}

// ------- gate GEMM: sigmoid -> bf16 out + per-row partial sums -----------
__global__ __launch_bounds__(256) void gemm_gate_k(
    const ushort* __restrict__ A, const ushort* __restrict__ Bt,
    const float* __restrict__ bias, ushort* __restrict__ Cb, int ldc, int K,
    float* __restrict__ gpart) {
  __shared__ __align__(16) ushort sh[32768];
  int tid = threadIdx.x, lane = tid & 63, w = tid >> 6;
  int m0 = blockIdx.y * BM, n0 = blockIdx.x * BN;
  int wr = w >> 1, wc = w & 1;
  GEMM_LOOP128(A, Bt, m0, n0, K)
  int lr = lane & 15, lg = lane >> 4;
  float* rs2 = (float*)sh;  // [2][128]
#pragma unroll
  for (int i = 0; i < 4; i++) {
#pragma unroll
    for (int r = 0; r < 4; r++) {
      float rsum = 0.0f;
      int row = m0 + wr * 64 + i * 16 + lg * 4 + r;
#pragma unroll
      for (int j2 = 0; j2 < 4; j2++) {
        int col = n0 + wc * 64 + j2 * 16 + lr;
        float v = 1.0f / (1.0f + __expf(-(acc[i][j2][r] + bias[col])));
        rsum += v;
        Cb[(size_t)row * ldc + col] = f2bf(v);
      }
#pragma unroll
      for (int o = 1; o < 16; o <<= 1) rsum += __shfl_xor(rsum, o, 64);
      if (lr == 0) rs2[wc * 128 + wr * 64 + i * 16 + lg * 4 + r] = rsum;
    }
  }
  __syncthreads();
  if (tid < 128)
    gpart[(size_t)(m0 + tid) * 8 + blockIdx.x] = rs2[tid] + rs2[128 + tid];
}

// ---------------- qkv GEMM with LDS-staged coalesced epilogue ------------
__global__ __launch_bounds__(256) void gemm_qkv_k(
    const ushort* __restrict__ A, const ushort* __restrict__ Bt,
    const float* __restrict__ bias, const ushort* __restrict__ gate_b,
    const float* __restrict__ gpart,
    ushort* __restrict__ qb, ushort* __restrict__ kb,
    ushort* __restrict__ kt, ushort* __restrict__ vt, int K) {
  __shared__ __align__(16) ushort sh[32768];
  __shared__ float ginvs[128];
  int tid = threadIdx.x, lane = tid & 63, w = tid >> 6;
  int m0 = blockIdx.y * BM, n0 = blockIdx.x * BN;
  int wr = w >> 1, wc = w & 1;
  GEMM_LOOP128(A, Bt, m0, n0, K)
  // ---- epilogue ----
  int region = n0 >> 10;  // 0=q, 1=k, 2=v
  int n0b = n0 & 1023;
  int h0 = n0b >> 6;
  if (region < 2) {
    if (tid < 128) {
      const float4* gp = (const float4*)&gpart[(size_t)(m0 + tid) * 8];
      float4 s0 = gp[0], s1 = gp[1];
      float s = s0.x + s0.y + s0.z + s0.w + s1.x + s1.y + s1.z + s1.w;
      ginvs[tid] = 1.0f / (s * (1.0f / DM) + EPSF);
    }
#pragma unroll
    for (int it = 0; it < 8; it++) {
      int e = it * 256 + tid;
      int row = e >> 4, ch = e & 15;
      *(short8*)&sh[row * 132 + ch * 8] =
          *(const short8*)&gate_b[(size_t)(m0 + row) * DM + n0b + ch * 8];
    }
    __syncthreads();
#pragma unroll
    for (int i = 0; i < 4; i++) {
#pragma unroll
      for (int j2 = 0; j2 < 4; j2++) {
        int cl = wc * 64 + j2 * 16 + (lane & 15);
        float bv = bias[n0 + cl];
        int rl0 = wr * 64 + i * 16 + (lane >> 4) * 4;
#pragma unroll
        for (int r = 0; r < 4; r++) {
          float gv = bf2f(sh[(rl0 + r) * 132 + cl]) * ginvs[rl0 + r];
          float v = (acc[i][j2][r] + bv) * gv;
          v = fmaxf(v, 0.0f);
          acc[i][j2][r] = v * v + EPSF;
        }
      }
    }
    __syncthreads();
  } else {
#pragma unroll
    for (int i = 0; i < 4; i++)
#pragma unroll
      for (int j2 = 0; j2 < 4; j2++) {
        int cl = wc * 64 + j2 * 16 + (lane & 15);
        float bv = bias[n0 + cl];
#pragma unroll
        for (int r = 0; r < 4; r++) acc[i][j2][r] += bv;
      }
  }
  // pack C tile into LDS, swizzled
#pragma unroll
  for (int i = 0; i < 4; i++) {
#pragma unroll
    for (int j2 = 0; j2 < 4; j2++) {
      int cl = wc * 64 + j2 * 16 + (lane & 15);
      int rl0 = wr * 64 + i * 16 + (lane >> 4) * 4;
#pragma unroll
      for (int r = 0; r < 4; r++) {
        int row = rl0 + r;
        sh[row * 128 + (cl ^ cswz(row))] = f2bf(acc[i][j2][r]);
      }
    }
  }
  __syncthreads();
  // coalesced stores
  if (region < 2) {
    ushort* dstRM = (region == 0) ? qb : kb;
#pragma unroll
    for (int it = 0; it < 8; it++) {
      int e = it * 256 + tid;
      int row = e >> 4, ch = e & 15;
      short8 val = *(const short8*)&sh[row * 128 + ((ch * 8) ^ cswz(row))];
      int tglob = m0 + row;
      size_t bh2 = (size_t)(tglob >> 11) * 16 + h0 + (ch >> 3);
      *(short8*)&dstRM[(bh2 * 2048 + (tglob & 2047)) * 64 + (ch & 7) * 8] = val;
    }
  }
  if (region >= 1) {
    ushort* dstT = (region == 1) ? kt : vt;
#pragma unroll
    for (int it = 0; it < 8; it++) {
      int e = it * 256 + tid;
      int tch = e & 15, dkrow = e >> 4;
      short8 val;
#pragma unroll
      for (int j = 0; j < 8; j++) {
        int row = tch * 8 + j;
        val[j] = (short)sh[row * 128 + (dkrow ^ cswz(row))];
      }
      int tglob0 = m0 + tch * 8;
      size_t bh2 = (size_t)(tglob0 >> 11) * 16 + h0 + (dkrow >> 6);
      *(short8*)&dstT[(bh2 * 64 + (dkrow & 63)) * 2048 + (tglob0 & 2047)] = val;
    }
  }
}

// ---- fused chunk-KV + exclusive prefix (running prefix = MFMA C-operand) --
// 2-deep chunk prefetch.
__global__ __launch_bounds__(256) void chunkpfx_k(const ushort* __restrict__ kt,
                                                  const ushort* __restrict__ vt,
                                                  ushort* __restrict__ KVb,
                                                  float* __restrict__ ksum) {
  int bid = blockIdx.x;
  int bh = (bid & 7) | ((bid >> 5) << 3);
  int dvs = (bid >> 3) & 3;
  int tid = threadIdx.x, l = tid & 63, w = tid >> 6;
  int lg = l >> 4;
  const ushort* vT = vt + ((size_t)bh * 64 + dvs * 16 + (l & 15)) * 2048;
  const ushort* kT = kt + ((size_t)bh * 64 + w * 16 + (l & 15)) * 2048;
  f32x4 run = {0.f, 0.f, 0.f, 0.f};
  float runks = 0.0f;
  short8 a0 = *(const short8*)&vT[lg * 8];
  short8 a1 = *(const short8*)&vT[32 + lg * 8];
  short8 b0 = *(const short8*)&kT[lg * 8];
  short8 b1 = *(const short8*)&kT[32 + lg * 8];
  short8 na0 = *(const short8*)&vT[64 + lg * 8];
  short8 na1 = *(const short8*)&vT[96 + lg * 8];
  short8 nb0 = *(const short8*)&kT[64 + lg * 8];
  short8 nb1 = *(const short8*)&kT[96 + lg * 8];
  for (int c = 0; c < 32; c++) {
    ushort* dst = KVb + ((size_t)bh * 32 + c) * 4096 +
                  (size_t)(dvs * 16 + lg * 4) * 64 + w * 16 + (l & 15);
    dst[0] = f2bf(run[0]); dst[64] = f2bf(run[1]);
    dst[128] = f2bf(run[2]); dst[192] = f2bf(run[3]);
    if (dvs == 0) {
      float s = 0.f;
#pragma unroll
      for (int j = 0; j < 8; j++) s += bf2f((ushort)b0[j]) + bf2f((ushort)b1[j]);
      s += __shfl_xor(s, 16, 64);
      s += __shfl_xor(s, 32, 64);
      if (l < 16) ksum[((size_t)bh * 32 + c) * 64 + w * 16 + l] = runks;
      runks += s;
    }
    int cn = (c + 2) & 31;  // clamped prefetch (wraps on last 2 iters, unused)
    short8 ta0 = *(const short8*)&vT[cn * 64 + lg * 8];
    short8 ta1 = *(const short8*)&vT[cn * 64 + 32 + lg * 8];
    short8 tb0 = *(const short8*)&kT[cn * 64 + lg * 8];
    short8 tb1 = *(const short8*)&kT[cn * 64 + 32 + lg * 8];
    run = __builtin_amdgcn_mfma_f32_16x16x32_bf16(a0, b0, run, 0, 0, 0);
    run = __builtin_amdgcn_mfma_f32_16x16x32_bf16(a1, b1, run, 0, 0, 0);
    a0 = na0; a1 = na1; b0 = nb0; b1 = nb1;
    na0 = ta0; na1 = ta1; nb0 = tb0; nb1 = tb1;
  }
}

// ---------------- pass 3: O^T[dv][t] = KVb·Q + vt·S, S^T = mfma(K,Q) ------
__global__ __launch_bounds__(256) void attn_k(
    const ushort* __restrict__ qb, const ushort* __restrict__ kb,
    const ushort* __restrict__ vt, const ushort* __restrict__ KVb,
    const float* __restrict__ ks, ushort* __restrict__ attnout) {
  int c = blockIdx.x, bh = blockIdx.y;
  int b = bh >> 4, h = bh & 15;
  const ushort* qB = qb + ((size_t)bh * 2048 + (size_t)c * 64) * 64;
  const ushort* kB = kb + ((size_t)bh * 2048 + (size_t)c * 64) * 64;
  const ushort* vT = vt + (size_t)bh * 64 * 2048 + (size_t)c * 64;
  const ushort* kvB = KVb + ((size_t)bh * 32 + c) * 4096;
  const float* ksP = ks + ((size_t)bh * 32 + c) * 64;
  __shared__ __align__(16) char SL[64 * 128];
  __shared__ float denp[4][64];
  __shared__ float den2p[4][64];
  __shared__ float invden[64];
  int tid = threadIdx.x, l = tid & 63, w = tid >> 6;
  int lr = l & 15, lg = l >> 4;
  {
    short8 q0 = *(const short8*)&qB[(size_t)l * 64 + w * 16];
    short8 q1 = *(const short8*)&qB[(size_t)l * 64 + w * 16 + 8];
    float d2 = 0.0f;
#pragma unroll
    for (int j = 0; j < 8; j++) {
      d2 += bf2f((ushort)q0[j]) * ksP[w * 16 + j];
      d2 += bf2f((ushort)q1[j]) * ksP[w * 16 + 8 + j];
    }
    den2p[w][l] = d2;
  }
#pragma unroll
  for (int n = 0; n < 4; n++) {
    f32x4 sa = {0.f, 0.f, 0.f, 0.f};
#pragma unroll
    for (int g = 0; g < 2; g++) {
      short8 a = *(const short8*)&kB[(size_t)(w * 16 + lr) * 64 + g * 32 + lg * 8];
      short8 bq = *(const short8*)&qB[(size_t)(n * 16 + lr) * 64 + g * 32 + lg * 8];
      sa = __builtin_amdgcn_mfma_f32_16x16x32_bf16(a, bq, sa, 0, 0, 0);
    }
    int t = n * 16 + lr;
    int s0 = w * 16 + lg * 4;
    float dsum = 0.0f;
    ushort sb[4];
#pragma unroll
    for (int r = 0; r < 4; r++) {
      float v = (s0 + r <= t) ? sa[r] : 0.0f;
      dsum += v;
      sb[r] = f2bf(v);
    }
    dsum += __shfl_xor(dsum, 16, 64);
    dsum += __shfl_xor(dsum, 32, 64);
    if (l < 16) denp[w][n * 16 + l] = dsum;
    int u = (s0 >> 3) ^ (t & 7);
    uint2 p;
    p.x = sb[0] | ((unsigned)sb[1] << 16);
    p.y = sb[2] | ((unsigned)sb[3] << 16);
    *(uint2*)&SL[t * 128 + u * 16 + (s0 & 7) * 2] = p;
  }
  __syncthreads();
  if (tid < 64) {
    float den = denp[0][tid] + denp[1][tid] + denp[2][tid] + denp[3][tid] +
                den2p[0][tid] + den2p[1][tid] + den2p[2][tid] + den2p[3][tid] + EPSF;
    invden[tid] = 1.0f / den;
  }
  __syncthreads();
#pragma unroll
  for (int n = 0; n < 4; n++) {
    f32x4 oa = {0.f, 0.f, 0.f, 0.f};
#pragma unroll
    for (int g = 0; g < 2; g++) {
      short8 a = *(const short8*)&kvB[(size_t)(w * 16 + lr) * 64 + g * 32 + lg * 8];
      short8 bq = *(const short8*)&qB[(size_t)(n * 16 + lr) * 64 + g * 32 + lg * 8];
      oa = __builtin_amdgcn_mfma_f32_16x16x32_bf16(a, bq, oa, 0, 0, 0);
    }
    int t = n * 16 + lr;
#pragma unroll
    for (int g = 0; g < 2; g++) {
      short8 a = *(const short8*)&vT[(size_t)(w * 16 + lr) * 2048 + g * 32 + lg * 8];
      int u = (g * 4 + lg) ^ (t & 7);
      short8 bs = *(const short8*)&SL[t * 128 + u * 16];
      oa = __builtin_amdgcn_mfma_f32_16x16x32_bf16(a, bs, oa, 0, 0, 0);
    }
    float iv = invden[t];
    ushort ob[4];
#pragma unroll
    for (int r = 0; r < 4; r++) ob[r] = f2bf(oa[r] * iv);
    size_t tok = (size_t)b * 2048 + (size_t)c * 64 + t;
    uint2 p;
    p.x = ob[0] | ((unsigned)ob[1] << 16);
    p.y = ob[2] | ((unsigned)ob[3] << 16);
    *(uint2*)&attnout[tok * 1024 + h * 64 + w * 16 + lg * 4] = p;
  }
}

extern "C" void kernel_launch(void* const* d_in, const int* in_sizes, int n_in,
                              void* d_out, int out_size, void* d_ws, size_t ws_size,
                              hipStream_t stream) {
  const float* x      = (const float*)d_in[0];
  const float* ln_g   = (const float*)d_in[1];
  const float* ln_b   = (const float*)d_in[2];
  const float* W_qkv  = (const float*)d_in[3];
  const float* b_qkv  = (const float*)d_in[4];
  const float* W_gate = (const float*)d_in[5];
  const float* b_gate = (const float*)d_in[6];
  const float* W_proj = (const float*)d_in[7];
  const float* b_proj = (const float*)d_in[8];
  float* out = (float*)d_out;

  char* wsb = (char*)d_ws;
  const size_t TD = (size_t)TOK * DM;
  const size_t SLOT = TD * 2;
  ushort* x_b     = (ushort*)(wsb + 0 * SLOT);  // dead after gate GEMM
  ushort* attnout = (ushort*)(wsb + 0 * SLOT);
  ushort* xn_b    = (ushort*)(wsb + 1 * SLOT);
  ushort* qb      = (ushort*)(wsb + 2 * SLOT);
  ushort* kb      = (ushort*)(wsb + 3 * SLOT);
  ushort* kt      = (ushort*)(wsb + 4 * SLOT);
  ushort* vt      = (ushort*)(wsb + 5 * SLOT);
  ushort* gate_b  = (ushort*)(wsb + 6 * SLOT);  // slots 6-7
  // slot 8: Wt_qkv @0 (6.3MB) + Wt_gate @8MB (2.1MB); both dead -> KVb
  ushort* Wt_qkv  = (ushort*)(wsb + 8 * SLOT);
  ushort* Wt_gate = (ushort*)(wsb + 8 * SLOT + (size_t)8 * 1024 * 1024);
  ushort* KVb     = (ushort*)(wsb + 8 * SLOT);
  ushort* Wt_proj = (ushort*)(wsb + 9 * SLOT);
  float*  ksum    = (float*)(wsb + 9 * SLOT + (size_t)8 * 1024 * 1024);   // 512 KB
  float*  gpart   = (float*)(wsb + 9 * SLOT + (size_t)12 * 1024 * 1024);  // 256 KB

  // 1) LayerNorm + x->bf16 + all weight transposes, one launch
  prep_k<<<8192 + 5120, 256, 0, stream>>>(x, ln_g, ln_b, x_b, xn_b,
                                          W_gate, W_qkv, W_proj,
                                          Wt_gate, Wt_qkv, Wt_proj);
  // 2) gate = sigmoid(x @ W_gate + b_gate) -> bf16, + per-row partial sums
  gemm_gate_k<<<dim3(DM / BN, TOK / BM), 256, 0, stream>>>(x_b, Wt_gate, b_gate,
                                                           gate_b, DM, DM, gpart);
  // 3) qkv GEMM -> qb/kb + kt/vt (bf16), fused gate*ginv+relu^2
  gemm_qkv_k<<<dim3(3 * DM / BN, TOK / BM), 256, 0, stream>>>(xn_b, Wt_qkv, b_qkv, gate_b,
                                                              gpart, qb, kb, kt, vt, DM);
  // 4) fused chunk-KV + exclusive prefix -> KVb (bf16) + ksum (fp32)
  chunkpfx_k<<<256, 256, 0, stream>>>(kt, vt, KVb, ksum);
  // 5) chunk outputs -> attnout bf16 row-major
  attn_k<<<dim3(32, 64), 256, 0, stream>>>(qb, kb, vt, KVb, ksum, attnout);
  // 6) out = attn @ W_proj + b_proj (fp32 out)
  gemm_bf16_k<<<dim3(DM / BN, TOK / BM), 256, 0, stream>>>(attnout, Wt_proj, b_proj, out,
                                                           DM, DM);
}